// Round 1
// 812.925 us; speedup vs baseline: 1.6723x; 1.6723x over previous
//
#include <hip/hip_runtime.h>
#include <hip/hip_bf16.h>

// ScaledDotProductAttention: B=2,H=16,S=2048,D=64 -> (output[B,H,S,D], weights[B,H,S,S]).
// Inputs float32, outputs FLOAT32. Two-pass flash-with-weights, bf16 MFMA 16x16x32.
// R3: latency-bound fix. 16-row wave tiles (grid 512->1024 blocks, 4 blocks/CU,
// __launch_bounds__(256,4)); mask + K staged in LDS with coalesced wide loads
// (replaces ~2048 scalar global byte-loads/lane); XCD-chunked block swizzle.
// Numerics bit-identical to previous passing kernel.

namespace {

constexpr int kS = 2048;
constexpr int kD = 64;
constexpr int kBH = 32;            // B*H
constexpr int kTQW = 16;           // q rows per wave
constexpr int kNW = 4;             // waves per block
constexpr int kTQB = kTQW * kNW;   // 64 q rows per block
constexpr int kChunk = 64;         // k rows per chunk
constexpr int kNB = kBH * (kS / kTQB);           // 1024 blocks
constexpr size_t kWOff = (size_t)kBH * kS * kD;  // weights offset in d_out

typedef __attribute__((ext_vector_type(8))) short bf16x8;
typedef __attribute__((ext_vector_type(4))) float f32x4;

__device__ inline short f2bf(float f) {
  union { float f; unsigned u; } x; x.f = f;
  return (short)((x.u + 0x7fffu + ((x.u >> 16) & 1u)) >> 16);  // RNE
}

__device__ inline bf16x8 load8_bf16(const float* p, float scale) {
  float4 x0 = *(const float4*)p;
  float4 x1 = *(const float4*)(p + 4);
  bf16x8 f;
  f[0] = f2bf(x0.x * scale); f[1] = f2bf(x0.y * scale);
  f[2] = f2bf(x0.z * scale); f[3] = f2bf(x0.w * scale);
  f[4] = f2bf(x1.x * scale); f[5] = f2bf(x1.y * scale);
  f[6] = f2bf(x1.z * scale); f[7] = f2bf(x1.w * scale);
  return f;
}

__global__ __launch_bounds__(256, 4) void attn_fused(
    const float* __restrict__ qg, const float* __restrict__ kg,
    const float* __restrict__ vg, const unsigned int* __restrict__ mg,
    float* __restrict__ outg) {
  // 144 B row stride (16B-aligned, 36 dwords -> bank-spread); Msk 80 B rows (16B-aligned).
  __shared__ __align__(16) short Kt[kChunk][72];          // bf16 K[krel][d]
  __shared__ __align__(16) short Vt[kD][72];              // bf16 V^T [d][krel]
  __shared__ __align__(16) short Wt[kNW][kTQW][72];       // per-wave weights [qlocal][krel]
  __shared__ __align__(16) unsigned char Msk[kChunk][80]; // mask bytes [qlocal(block)][krel]

  const int tid  = threadIdx.x;
  const int wv   = tid >> 6;
  const int lane = tid & 63;
  const int l15  = lane & 15;
  const int quad = lane >> 4;

  // XCD-chunked swizzle: consecutive work (same bh) lands on one XCD's L2. 1024%8==0 -> bijective.
  const int bid  = blockIdx.x;
  const int work = ((bid & 7) << 7) | (bid >> 3);
  const int qt   = work & 31;       // 32 q tiles of 64 rows
  const int bh   = work >> 5;
  const int b    = bh >> 4;         // H = 16
  const int q0b  = qt * kTQB;       // block q start (row within bh)

  // ---- mask encoding detection from first 64 words (same logic as prior passing kernel) ----
  // uint8 bools | int32 0/1 | float32 0/1.0 | bf16 0/1.0. Consumer test is element-granular !=0.
  int allW32 = 1, allI32 = 1, allBF = 1;
#pragma unroll
  for (int i = 0; i < 64; ++i) {
    const unsigned u = mg[i];
    const unsigned lo = u & 0xFFFFu, hi = u >> 16;
    allW32 &= (int)(u == 0u || u == 0x3F800000u);
    allI32 &= (int)(u == 0u || u == 1u);
    allBF  &= (int)((lo == 0u || lo == 0x3F80u) && (hi == 0u || hi == 0x3F80u));
  }
  int msz;
  if (allI32)      msz = 4;   // int32 0/1
  else if (allW32) msz = 4;   // float32 0/1.0 (check before bf16 superset)
  else if (allBF)  msz = 2;   // bf16 0/1.0
  else             msz = 1;   // packed uint8 bools
  const unsigned char* mB = (const unsigned char*)mg + (size_t)b * kS * kS * msz;

  const float* qbase = qg + (size_t)bh * kS * kD;
  const float* kbase = kg + (size_t)bh * kS * kD;
  const float* vbase = vg + (size_t)bh * kS * kD;
  float* obase = outg + (size_t)bh * kS * kD;
  float* wbase = outg + kWOff + (size_t)bh * kS * kS;

  // ---- Q A-fragments, pre-scaled by 1/8 (exact), in registers ----
  bf16x8 aq[2];
#pragma unroll
  for (int dh = 0; dh < 2; ++dh)
    aq[dh] = load8_bf16(qbase + (size_t)(q0b + wv * kTQW + l15) * kD + dh * 32 + quad * 8, 0.125f);

  // cooperative staging indices: thread -> (row si, 16-elem segment sj)
  const int si = tid >> 2;          // 0..63
  const int sj = (tid & 3) << 4;    // 0,16,32,48

  auto stage_k = [&](int k0) {
    const float* p = kbase + (size_t)(k0 + si) * kD + sj;
    *(bf16x8*)&Kt[si][sj]     = load8_bf16(p, 1.0f);
    *(bf16x8*)&Kt[si][sj + 8] = load8_bf16(p + 8, 1.0f);
  };

  auto stage_v = [&](int k0) {
    const float* p = vbase + (size_t)(k0 + si) * kD + sj;
#pragma unroll
    for (int i = 0; i < 4; ++i) {
      float4 x = *(const float4*)(p + 4 * i);
      Vt[sj + 4 * i + 0][si] = f2bf(x.x);
      Vt[sj + 4 * i + 1][si] = f2bf(x.y);
      Vt[sj + 4 * i + 2][si] = f2bf(x.z);
      Vt[sj + 4 * i + 3][si] = f2bf(x.w);
    }
  };

  auto stage_mask = [&](int k0) {
    const size_t eoff = (size_t)(q0b + si) * kS + (size_t)(k0 + sj);
    if (msz == 1) {
      *(uint4*)&Msk[si][sj] = *(const uint4*)(mB + eoff);          // bytes already 0/1
    } else if (msz == 4) {
      const unsigned int* p = (const unsigned int*)mB + eoff;      // works for int32 AND f32
      unsigned int* dst = (unsigned int*)&Msk[si][sj];
#pragma unroll
      for (int g = 0; g < 4; ++g) {
        uint4 e = *(const uint4*)(p + 4 * g);
        dst[g] = (e.x ? 1u : 0u) | ((e.y ? 1u : 0u) << 8) |
                 ((e.z ? 1u : 0u) << 16) | ((e.w ? 1u : 0u) << 24);
      }
    } else {  // msz == 2, bf16 0/1.0
      const unsigned int* p = (const unsigned int*)((const unsigned short*)mB + eoff);
      unsigned int* dst = (unsigned int*)&Msk[si][sj];
#pragma unroll
      for (int g = 0; g < 4; ++g) {
        const unsigned int a = p[2 * g], c = p[2 * g + 1];
        dst[g] = ((a & 0xFFFFu) ? 1u : 0u) | (((a >> 16) ? 1u : 0u) << 8) |
                 (((c & 0xFFFFu) ? 1u : 0u) << 16) | (((c >> 16) ? 1u : 0u) << 24);
      }
    }
  };

  // ================= Pass A: l = sum_k exp(s) per q row =================
  float lsum[4] = {0.f, 0.f, 0.f, 0.f};
  for (int k0 = 0; k0 < kS; k0 += kChunk) {
    __syncthreads();                 // previous chunk's LDS reads complete
    stage_k(k0);
    stage_mask(k0);
    __syncthreads();
#pragma unroll
    for (int cg = 0; cg < 4; ++cg) {
      bf16x8 bk0 = *(const bf16x8*)&Kt[cg * 16 + l15][quad * 8];
      bf16x8 bk1 = *(const bf16x8*)&Kt[cg * 16 + l15][32 + quad * 8];
      f32x4 acc = {0.f, 0.f, 0.f, 0.f};
      acc = __builtin_amdgcn_mfma_f32_16x16x32_bf16(aq[0], bk0, acc, 0, 0, 0);
      acc = __builtin_amdgcn_mfma_f32_16x16x32_bf16(aq[1], bk1, acc, 0, 0, 0);
      // C/D: lane holds S[row = quad*4 + r][col = l15]
#pragma unroll
      for (int r = 0; r < 4; ++r) {
        const int lrow = wv * kTQW + quad * 4 + r;
        const float e = __expf(acc[r]);
        // masked -> s = -1e-9 -> exp rounds to exactly 1.0f in fp32
        lsum[r] += (Msk[lrow][cg * 16 + l15] != 0) ? 1.0f : e;
      }
    }
  }

  float inv_l[4];
#pragma unroll
  for (int r = 0; r < 4; ++r) {
    float t = lsum[r];
    t += __shfl_xor(t, 1, 16);
    t += __shfl_xor(t, 2, 16);
    t += __shfl_xor(t, 4, 16);
    t += __shfl_xor(t, 8, 16);
    inv_l[r] = 1.0f / t;
  }

  // ================= Pass B: weights out (fp32) + PV =================
  f32x4 acco[4];
#pragma unroll
  for (int d = 0; d < 4; ++d) acco[d] = (f32x4){0.f, 0.f, 0.f, 0.f};

  for (int k0 = 0; k0 < kS; k0 += kChunk) {
    __syncthreads();                 // previous chunk's Kt/Vt/Msk reads complete
    stage_k(k0);
    stage_v(k0);
    stage_mask(k0);
    __syncthreads();
#pragma unroll
    for (int cg = 0; cg < 4; ++cg) {
      bf16x8 bk0 = *(const bf16x8*)&Kt[cg * 16 + l15][quad * 8];
      bf16x8 bk1 = *(const bf16x8*)&Kt[cg * 16 + l15][32 + quad * 8];
      f32x4 acc = {0.f, 0.f, 0.f, 0.f};
      acc = __builtin_amdgcn_mfma_f32_16x16x32_bf16(aq[0], bk0, acc, 0, 0, 0);
      acc = __builtin_amdgcn_mfma_f32_16x16x32_bf16(aq[1], bk1, acc, 0, 0, 0);
      const int kcol = k0 + cg * 16 + l15;
#pragma unroll
      for (int r = 0; r < 4; ++r) {
        const int lrow = wv * kTQW + quad * 4 + r;
        const float e = __expf(acc[r]);
        const float w = ((Msk[lrow][cg * 16 + l15] != 0) ? 1.0f : e) * inv_l[r];
        wbase[(size_t)(q0b + lrow) * kS + kcol] = w;                // fp32 weights
        Wt[wv][quad * 4 + r][cg * 16 + l15] = f2bf(w);              // bf16 for PV
      }
    }
    // PV: Wt written+read by the SAME wave only -> no block barrier needed
    // (compiler inserts lgkmcnt wait for the LDS dependency).
#pragma unroll
    for (int ks = 0; ks < 2; ++ks) {
      bf16x8 aw = *(const bf16x8*)&Wt[wv][l15][ks * 32 + quad * 8];
#pragma unroll
      for (int d = 0; d < 4; ++d) {
        bf16x8 bv = *(const bf16x8*)&Vt[d * 16 + l15][ks * 32 + quad * 8];
        acco[d] = __builtin_amdgcn_mfma_f32_16x16x32_bf16(aw, bv, acco[d], 0, 0, 0);
      }
    }
  }

  // ---- epilogue: store O (fp32) ----
#pragma unroll
  for (int d = 0; d < 4; ++d)
#pragma unroll
    for (int r = 0; r < 4; ++r)
      obase[(size_t)(q0b + wv * kTQW + quad * 4 + r) * kD + d * 16 + l15] = acco[d][r];
}

}  // namespace

extern "C" void kernel_launch(void* const* d_in, const int* in_sizes, int n_in,
                              void* d_out, int out_size, void* d_ws, size_t ws_size,
                              hipStream_t stream) {
  const float* q = (const float*)d_in[0];
  const float* k = (const float*)d_in[1];
  const float* v = (const float*)d_in[2];
  const unsigned int* mask = (const unsigned int*)d_in[3];
  float* out = (float*)d_out;  // fp32 output buffer (output ++ weights)
  attn_fused<<<dim3(kNB), dim3(256), 0, stream>>>(q, k, v, mask, out);
}

// Round 2
// 790.873 us; speedup vs baseline: 1.7190x; 1.0279x over previous
//
#include <hip/hip_runtime.h>
#include <hip/hip_bf16.h>

// ScaledDotProductAttention: B=2,H=16,S=2048,D=64 -> (output[B,H,S,D], weights[B,H,S,S]).
// Inputs float32, outputs FLOAT32. Two-pass flash-with-weights, bf16 MFMA 16x16x32.
// R4: stall removal. (1) T14 async-stage double-buffer: next chunk's K/V/mask loaded into
// registers during current chunk's compute, LDS-written after the barrier -> HBM latency
// hidden. (2) Non-temporal weights/O stores -> stop L2 thrash of K/V/mask working set.
// (3) stage_v rewritten: paired-row ds_write_b32 + XOR pair-swizzle -> ~2-way banks
// (was 16x ds_write_b16 8-way). Numerics bit-identical to R3 passing kernel.

namespace {

constexpr int kS = 2048;
constexpr int kD = 64;
constexpr int kBH = 32;            // B*H
constexpr int kTQW = 16;           // q rows per wave
constexpr int kNW = 4;             // waves per block
constexpr int kTQB = kTQW * kNW;   // 64 q rows per block
constexpr int kChunk = 64;         // k rows per chunk
constexpr int kNC = kS / kChunk;   // 32 chunks
constexpr int kNB = kBH * (kS / kTQB);           // 1024 blocks
constexpr size_t kWOff = (size_t)kBH * kS * kD;  // weights offset in d_out

typedef __attribute__((ext_vector_type(8))) short bf16x8;
typedef __attribute__((ext_vector_type(4))) float f32x4;

__device__ inline short f2bf(float f) {
  union { float f; unsigned u; } x; x.f = f;
  return (short)((x.u + 0x7fffu + ((x.u >> 16) & 1u)) >> 16);  // RNE
}

__device__ inline bf16x8 cvt8(float4 a, float4 b, float scale) {
  bf16x8 f;
  f[0] = f2bf(a.x * scale); f[1] = f2bf(a.y * scale);
  f[2] = f2bf(a.z * scale); f[3] = f2bf(a.w * scale);
  f[4] = f2bf(b.x * scale); f[5] = f2bf(b.y * scale);
  f[6] = f2bf(b.z * scale); f[7] = f2bf(b.w * scale);
  return f;
}

__global__ __launch_bounds__(256, 4) void attn_fused(
    const float* __restrict__ qg, const float* __restrict__ kg,
    const float* __restrict__ vg, const unsigned int* __restrict__ mg,
    float* __restrict__ outg) {
  // 144 B row stride (16B-aligned); Msk 80 B rows. Total 32768 B -> LDS allows 5 blocks/CU.
  __shared__ __align__(16) short Kt[kChunk][72];          // bf16 K[krel][d]
  __shared__ __align__(16) short Vt[kD][72];              // bf16 V^T [d][krel-pair swizzled]
  __shared__ __align__(16) short Wt[kNW][kTQW][72];       // per-wave weights [qlocal][krel]
  __shared__ __align__(16) unsigned char Msk[kChunk][80]; // mask bytes [qlocal(block)][krel]

  const int tid  = threadIdx.x;
  const int wv   = tid >> 6;
  const int lane = tid & 63;
  const int l15  = lane & 15;
  const int quad = lane >> 4;

  // XCD-chunked swizzle: blocks with bid%8==x (-> XCD x) get a contiguous work range
  // (4 bh per XCD: K+V working set ~4 MB = L2 size). 1024%8==0 -> bijective.
  const int bid  = blockIdx.x;
  const int work = ((bid & 7) << 7) | (bid >> 3);
  const int qt   = work & 31;       // 32 q tiles of 64 rows
  const int bh   = work >> 5;
  const int b    = bh >> 4;         // H = 16
  const int q0b  = qt * kTQB;       // block q start (row within bh)

  // ---- mask encoding detection (uint8 | int32 | float32 | bf16), element test != 0 ----
  int allW32 = 1, allI32 = 1, allBF = 1;
#pragma unroll
  for (int i = 0; i < 64; ++i) {
    const unsigned u = mg[i];
    const unsigned lo = u & 0xFFFFu, hi = u >> 16;
    allW32 &= (int)(u == 0u || u == 0x3F800000u);
    allI32 &= (int)(u == 0u || u == 1u);
    allBF  &= (int)((lo == 0u || lo == 0x3F80u) && (hi == 0u || hi == 0x3F80u));
  }
  int msz;
  if (allI32)      msz = 4;   // int32 0/1
  else if (allW32) msz = 4;   // float32 0/1.0 (check before bf16 superset)
  else if (allBF)  msz = 2;   // bf16 0/1.0
  else             msz = 1;   // packed uint8 bools
  const unsigned char* mB = (const unsigned char*)mg + (size_t)b * kS * kS * msz;

  const float* qbase = qg + (size_t)bh * kS * kD;
  const float* kbase = kg + (size_t)bh * kS * kD;
  const float* vbase = vg + (size_t)bh * kS * kD;
  float* obase = outg + (size_t)bh * kS * kD;
  float* wbase = outg + kWOff + (size_t)bh * kS * kS;

  // ---- Q A-fragments, pre-scaled by 1/8 (exact), in registers ----
  bf16x8 aq[2];
#pragma unroll
  for (int dh = 0; dh < 2; ++dh) {
    const float* p = qbase + (size_t)(q0b + wv * kTQW + l15) * kD + dh * 32 + quad * 8;
    aq[dh] = cvt8(*(const float4*)p, *(const float4*)(p + 4), 0.125f);
  }

  // staging thread maps
  const int si = tid >> 2;          // K/M row 0..63
  const int sj = (tid & 3) << 4;    // K col segment 0/16/32/48
  const int vd = (tid & 7) << 3;    // V: d base 0..56
  const int vk = (tid >> 3) << 1;   // V: even krel (pair base) 0..62

  // ---- register double-buffer staging (T14: issue early, LDS-write late) ----
  float4 rk[4], rv[4];
  uint4 rmq;

  auto k_issue = [&](int k0) {
    const float* p = kbase + (size_t)(k0 + si) * kD + sj;
    rk[0] = ((const float4*)p)[0];
    rk[1] = *(const float4*)(p + 4);
    rk[2] = *(const float4*)(p + 8);
    rk[3] = *(const float4*)(p + 12);
  };
  auto k_write = [&]() {
    *(bf16x8*)&Kt[si][sj]     = cvt8(rk[0], rk[1], 1.0f);
    *(bf16x8*)&Kt[si][sj + 8] = cvt8(rk[2], rk[3], 1.0f);
  };

  auto v_issue = [&](int k0) {
    const float* p = vbase + (size_t)(k0 + vk) * kD + vd;
    rv[0] = ((const float4*)p)[0];
    rv[1] = *(const float4*)(p + 4);
    rv[2] = *(const float4*)(p + kD);
    rv[3] = *(const float4*)(p + kD + 4);
  };
  // Transposed V: pair (krel=vk, vk+1) packed into one dword; pair index XOR-swizzled by
  // (dd>>3) so the 8 write rows land on ~2-way banks (write addr dword = dd*36 + ps).
  auto v_write = [&]() {
    const float* lo = (const float*)&rv[0];   // 8 floats, row vk
    const float* hi = (const float*)&rv[2];   // 8 floats, row vk+1
#pragma unroll
    for (int d = 0; d < 8; ++d) {
      const int dd = vd + d;
      const int ps = (vk >> 1) ^ (((dd >> 3) & 7) << 2);
      const unsigned u = (unsigned)(unsigned short)f2bf(lo[d]) |
                         ((unsigned)(unsigned short)f2bf(hi[d]) << 16);
      *(unsigned*)&Vt[dd][2 * ps] = u;
    }
  };

  auto m_issue = [&](int k0) {
    if (msz == 1)
      rmq = *(const uint4*)(mB + (size_t)(q0b + si) * kS + (size_t)(k0 + sj));
  };
  auto m_write = [&](int k0) {
    if (msz == 1) {
      *(uint4*)&Msk[si][sj] = rmq;   // bytes already 0/1
    } else if (msz == 4) {
      const size_t eoff = (size_t)(q0b + si) * kS + (size_t)(k0 + sj);
      const unsigned int* p = (const unsigned int*)mB + eoff;   // int32 AND f32: word != 0
      unsigned int* dst = (unsigned int*)&Msk[si][sj];
#pragma unroll
      for (int g = 0; g < 4; ++g) {
        uint4 e = *(const uint4*)(p + 4 * g);
        dst[g] = (e.x ? 1u : 0u) | ((e.y ? 1u : 0u) << 8) |
                 ((e.z ? 1u : 0u) << 16) | ((e.w ? 1u : 0u) << 24);
      }
    } else {  // msz == 2, bf16 0/1.0
      const size_t eoff = (size_t)(q0b + si) * kS + (size_t)(k0 + sj);
      const unsigned int* p = (const unsigned int*)((const unsigned short*)mB + eoff);
      unsigned int* dst = (unsigned int*)&Msk[si][sj];
#pragma unroll
      for (int g = 0; g < 4; ++g) {
        const unsigned int a = p[2 * g], c = p[2 * g + 1];
        dst[g] = ((a & 0xFFFFu) ? 1u : 0u) | (((a >> 16) ? 1u : 0u) << 8) |
                 (((c & 0xFFFFu) ? 1u : 0u) << 16) | (((c >> 16) ? 1u : 0u) << 24);
      }
    }
  };

  // ================= Pass A: l = sum_k exp(s) per q row =================
  float lsum[4] = {0.f, 0.f, 0.f, 0.f};
  k_issue(0);
  m_issue(0);
  for (int c = 0; c < kNC; ++c) {
    const int k0 = c * kChunk;
    __syncthreads();                 // previous chunk's LDS reads complete
    k_write();
    m_write(k0);
    if (c + 1 < kNC) { k_issue(k0 + kChunk); m_issue(k0 + kChunk); }  // fly during compute
    __syncthreads();                 // LDS ready
#pragma unroll
    for (int cg = 0; cg < 4; ++cg) {
      bf16x8 bk0 = *(const bf16x8*)&Kt[cg * 16 + l15][quad * 8];
      bf16x8 bk1 = *(const bf16x8*)&Kt[cg * 16 + l15][32 + quad * 8];
      f32x4 acc = {0.f, 0.f, 0.f, 0.f};
      acc = __builtin_amdgcn_mfma_f32_16x16x32_bf16(aq[0], bk0, acc, 0, 0, 0);
      acc = __builtin_amdgcn_mfma_f32_16x16x32_bf16(aq[1], bk1, acc, 0, 0, 0);
      // C/D: lane holds S[row = quad*4 + r][col = l15]
#pragma unroll
      for (int r = 0; r < 4; ++r) {
        const int lrow = wv * kTQW + quad * 4 + r;
        const float e = __expf(acc[r]);
        // masked -> s = -1e-9 -> exp rounds to exactly 1.0f in fp32
        lsum[r] += (Msk[lrow][cg * 16 + l15] != 0) ? 1.0f : e;
      }
    }
  }

  // preload pass-B chunk 0 now; latency hides under the shuffle reduce
  k_issue(0);
  v_issue(0);
  m_issue(0);

  float inv_l[4];
#pragma unroll
  for (int r = 0; r < 4; ++r) {
    float t = lsum[r];
    t += __shfl_xor(t, 1, 16);
    t += __shfl_xor(t, 2, 16);
    t += __shfl_xor(t, 4, 16);
    t += __shfl_xor(t, 8, 16);
    inv_l[r] = 1.0f / t;
  }

  // ================= Pass B: weights out (fp32, nontemporal) + PV =================
  f32x4 acco[4];
#pragma unroll
  for (int d = 0; d < 4; ++d) acco[d] = (f32x4){0.f, 0.f, 0.f, 0.f};

  for (int c = 0; c < kNC; ++c) {
    const int k0 = c * kChunk;
    __syncthreads();                 // previous chunk's Kt/Vt/Msk reads complete
    k_write();
    v_write();
    m_write(k0);
    if (c + 1 < kNC) { k_issue(k0 + kChunk); v_issue(k0 + kChunk); m_issue(k0 + kChunk); }
    __syncthreads();                 // LDS ready
#pragma unroll
    for (int cg = 0; cg < 4; ++cg) {
      bf16x8 bk0 = *(const bf16x8*)&Kt[cg * 16 + l15][quad * 8];
      bf16x8 bk1 = *(const bf16x8*)&Kt[cg * 16 + l15][32 + quad * 8];
      f32x4 acc = {0.f, 0.f, 0.f, 0.f};
      acc = __builtin_amdgcn_mfma_f32_16x16x32_bf16(aq[0], bk0, acc, 0, 0, 0);
      acc = __builtin_amdgcn_mfma_f32_16x16x32_bf16(aq[1], bk1, acc, 0, 0, 0);
      const int kcol = k0 + cg * 16 + l15;
#pragma unroll
      for (int r = 0; r < 4; ++r) {
        const int lrow = wv * kTQW + quad * 4 + r;
        const float e = __expf(acc[r]);
        const float w = ((Msk[lrow][cg * 16 + l15] != 0) ? 1.0f : e) * inv_l[r];
        __builtin_nontemporal_store(w, &wbase[(size_t)(q0b + lrow) * kS + kcol]);
        Wt[wv][quad * 4 + r][cg * 16 + l15] = f2bf(w);   // bf16 for PV
      }
    }
    // PV: Wt written+read by the SAME wave only -> no block barrier needed.
#pragma unroll
    for (int ks = 0; ks < 2; ++ks) {
      bf16x8 aw = *(const bf16x8*)&Wt[wv][l15][ks * 32 + quad * 8];
#pragma unroll
      for (int d = 0; d < 4; ++d) {
        const int dd = d * 16 + l15;
        const int psb = (ks * 16 + quad * 4) ^ (((dd >> 3) & 7) << 2);
        bf16x8 bv = *(const bf16x8*)&Vt[dd][2 * psb];
        acco[d] = __builtin_amdgcn_mfma_f32_16x16x32_bf16(aw, bv, acco[d], 0, 0, 0);
      }
    }
  }

  // ---- epilogue: store O (fp32, nontemporal) ----
#pragma unroll
  for (int d = 0; d < 4; ++d)
#pragma unroll
    for (int r = 0; r < 4; ++r)
      __builtin_nontemporal_store(
          acco[d][r],
          &obase[(size_t)(q0b + wv * kTQW + quad * 4 + r) * kD + d * 16 + l15]);
}

}  // namespace

extern "C" void kernel_launch(void* const* d_in, const int* in_sizes, int n_in,
                              void* d_out, int out_size, void* d_ws, size_t ws_size,
                              hipStream_t stream) {
  const float* q = (const float*)d_in[0];
  const float* k = (const float*)d_in[1];
  const float* v = (const float*)d_in[2];
  const unsigned int* mask = (const unsigned int*)d_in[3];
  float* out = (float*)d_out;  // fp32 output buffer (output ++ weights)
  attn_fused<<<dim3(kNB), dim3(256), 0, stream>>>(q, k, v, mask, out);
}